// Round 6
// baseline (226.310 us; speedup 1.0000x reference)
//
#include <hip/hip_runtime.h>
#include <hip/hip_bf16.h>
#include <math.h>

#define L_SEQ 1024
#define BSZ 8
#define EMB 512
#define NH 8
#define DQ 64
#define BH 64          // BSZ*NH
#define NQKV 1536      // 3*NH*DQ

// Q is pre-scaled by (emb_dim/n_head)^-0.5 * log2(e) so that
// softmax numerator = exp2(mfma_score) with zero extra VALU per element.
#define SCALE_Q 0.18033688f

typedef __attribute__((ext_vector_type(8))) short short8;   // 8 bf16 = 4 VGPR
typedef __attribute__((ext_vector_type(4))) float f32x4;

#define GPTR(x) ((const __attribute__((address_space(1))) void*)(x))
#define LPTR(x) ((__attribute__((address_space(3))) void*)(x))

__device__ __forceinline__ unsigned short bf16u(float x) {
  __hip_bfloat16 h = __float2bfloat16(x);
  return *(unsigned short*)&h;
}

// ---------------------------------------------------------------------------
// Kernel 0: f32 -> bf16 convert of emb (8192x512) and W (1536x512).
// ---------------------------------------------------------------------------
__global__ __launch_bounds__(256) void to_bf16(
    const float* __restrict__ emb, const float* __restrict__ W,
    unsigned short* __restrict__ embB, unsigned short* __restrict__ WB) {
  const size_t t = (size_t)blockIdx.x * 256 + threadIdx.x;
  size_t base = t * 8;
  const float* src;
  unsigned short* dst;
  size_t off;
  if (base < (size_t)8192 * 512) { src = emb; dst = embB; off = base; }
  else { src = W; dst = WB; off = base - (size_t)8192 * 512; }
  float4 v0 = *(const float4*)&src[off];
  float4 v1 = *(const float4*)&src[off + 4];
  short8 o;
  o[0] = bf16u(v0.x); o[1] = bf16u(v0.y); o[2] = bf16u(v0.z); o[3] = bf16u(v0.w);
  o[4] = bf16u(v1.x); o[5] = bf16u(v1.y); o[6] = bf16u(v1.z); o[7] = bf16u(v1.w);
  *(short8*)&dst[off] = o;
}

// ---------------------------------------------------------------------------
// Kernel A: QKV projection, bf16 MFMA (m97 pattern). Q gets SCALE_Q folded in.
// ---------------------------------------------------------------------------
__global__ __launch_bounds__(256) void qkv_mfma(
    const unsigned short* __restrict__ A,   // embB [8192][512]
    const unsigned short* __restrict__ B,   // WB   [1536][512]
    const float* __restrict__ bias,
    unsigned short* __restrict__ Qb, unsigned short* __restrict__ Kb,
    unsigned short* __restrict__ Vb) {
  __shared__ __align__(16) unsigned short As[128][32];  // 8 KB, unpadded
  __shared__ __align__(16) unsigned short Bs[128][32];  // 8 KB
  const int tid = threadIdx.x;
  const int wave = tid >> 6, lane = tid & 63;
  const int quad = lane >> 4, col = lane & 15;
  const int wr = wave >> 1, wc = wave & 1;
  const int m0 = blockIdx.y * 128, n0 = blockIdx.x * 128;
  const int r16 = lane >> 2, q4 = lane & 3;

  f32x4 acc[4][4] = {};

  for (int kt = 0; kt < EMB; kt += 32) {
    __syncthreads();
#pragma unroll
    for (int c = 0; c < 2; ++c) {
      const int rowA = (c * 4 + wave) * 16;
      __builtin_amdgcn_global_load_lds(
          GPTR(A + (size_t)(m0 + rowA + r16) * EMB + kt + q4 * 8),
          LPTR(&As[rowA][0]), 16, 0, 0);
      __builtin_amdgcn_global_load_lds(
          GPTR(B + (size_t)(n0 + rowA + r16) * EMB + kt + q4 * 8),
          LPTR(&Bs[rowA][0]), 16, 0, 0);
    }
    __syncthreads();
    short8 af[4], bf[4];
#pragma unroll
    for (int i = 0; i < 4; ++i)
      af[i] = *(const short8*)&As[wr * 64 + i * 16 + col][quad * 8];
#pragma unroll
    for (int j = 0; j < 4; ++j)
      bf[j] = *(const short8*)&Bs[wc * 64 + j * 16 + col][quad * 8];
#pragma unroll
    for (int i = 0; i < 4; ++i)
#pragma unroll
      for (int j = 0; j < 4; ++j)
        acc[i][j] =
            __builtin_amdgcn_mfma_f32_16x16x32_bf16(af[i], bf[j], acc[i][j],
                                                    0, 0, 0);
  }

#pragma unroll
  for (int j = 0; j < 4; ++j) {
    const int o = n0 + wc * 64 + j * 16 + col;
    const float bj = bias[o];
    const int h = o / 192;
    const int c2 = o - h * 192;
    const int sel = c2 >> 6, d = c2 & 63;
    unsigned short* dst = (sel == 0) ? Qb : (sel == 1) ? Kb : Vb;
#pragma unroll
    for (int i = 0; i < 4; ++i) {
      const int mrow = m0 + wr * 64 + i * 16 + quad * 4;
#pragma unroll
      for (int r = 0; r < 4; ++r) {
        const int row = mrow + r;
        const int l = row >> 3, bb = row & 7;
        float val = acc[i][j][r] + bj;
        if (sel == 0) val *= SCALE_Q;
        dst[(((size_t)(bb * NH + h)) * L_SEQ + l) * DQ + d] = bf16u(val);
      }
    }
  }
}

// ---------------------------------------------------------------------------
// Kernel B: two-pass MFMA attention-weight-sum, v5 (barrier-free sweeps).
// Block = (qc, bh). Wave w owns query rows qc*64 + w*16 .. +15 and sweeps
// ALL 1024 keys in both passes, loading K MFMA B-fragments DIRECTLY from
// global (no LDS staging, no barriers): all 4 waves read the same K stream,
// so L1/L2 serve it with 4x intra-block reuse. Pass 1: Z per row (complete
// within the wave -> butterfly over 16 col-lanes, no LDS exchange).
// Pass 2: colsums of exp2(s)*invz -> cs2[w][1024]; ONE barrier; reduce.
// A-layout: m=lane&15, k=quad*8+j. C/D: row=quad*4+reg, col=lane&15 (m89).
// ---------------------------------------------------------------------------
__global__ __launch_bounds__(256) void attn_2pass(
    const unsigned short* __restrict__ Qb, const unsigned short* __restrict__ Kb,
    float* __restrict__ part) {
  const int qc = blockIdx.x;   // 16
  const int bh = blockIdx.y;   // 64
  const int tid = threadIdx.x;
  const int wave = tid >> 6, lane = tid & 63;
  const int quad = lane >> 4, col = lane & 15;

  __shared__ float cs2[4][1024];  // 16 KB

  const unsigned short* kbase = &Kb[(size_t)bh * L_SEQ * DQ];

  // Q fragments for this wave's 16 rows (both passes)
  const unsigned short* qp =
      &Qb[((size_t)bh * L_SEQ + qc * 64 + wave * 16 + col) * DQ];
  short8 qa0 = *(const short8*)&qp[quad * 8];
  short8 qa1 = *(const short8*)&qp[32 + quad * 8];

  // ---------------- PASS 1: Z for this wave's 16 rows ----------------
  float zacc[4] = {0.f, 0.f, 0.f, 0.f};
#pragma unroll 4
  for (int g = 0; g < 64; ++g) {
    const unsigned short* kr = kbase + (size_t)(g * 16 + col) * DQ;
    short8 kb0 = *(const short8*)&kr[quad * 8];
    short8 kb1 = *(const short8*)&kr[32 + quad * 8];
    f32x4 s = {0.f, 0.f, 0.f, 0.f};
    s = __builtin_amdgcn_mfma_f32_16x16x32_bf16(qa0, kb0, s, 0, 0, 0);
    s = __builtin_amdgcn_mfma_f32_16x16x32_bf16(qa1, kb1, s, 0, 0, 0);
#pragma unroll
    for (int j = 0; j < 4; ++j) zacc[j] += __builtin_amdgcn_exp2f(s[j]);
  }
  float ivz[4];
#pragma unroll
  for (int j = 0; j < 4; ++j) {
    float z = zacc[j];
#pragma unroll
    for (int off = 1; off <= 8; off <<= 1) z += __shfl_xor(z, off, 64);
    ivz[j] = __builtin_amdgcn_rcpf(z);
  }

  // ---------------- PASS 2: colsums over this wave's 16 rows ----------
#pragma unroll 4
  for (int g = 0; g < 64; ++g) {
    const unsigned short* kr = kbase + (size_t)(g * 16 + col) * DQ;
    short8 kb0 = *(const short8*)&kr[quad * 8];
    short8 kb1 = *(const short8*)&kr[32 + quad * 8];
    f32x4 s = {0.f, 0.f, 0.f, 0.f};
    s = __builtin_amdgcn_mfma_f32_16x16x32_bf16(qa0, kb0, s, 0, 0, 0);
    s = __builtin_amdgcn_mfma_f32_16x16x32_bf16(qa1, kb1, s, 0, 0, 0);
    float partial = 0.f;
#pragma unroll
    for (int j = 0; j < 4; ++j)
      partial = fmaf(__builtin_amdgcn_exp2f(s[j]), ivz[j], partial);
    // sum over the 4 quads (16 rows); key index = g*16+col
    partial += __shfl_xor(partial, 16, 64);
    partial += __shfl_xor(partial, 32, 64);
    if (quad == 0) cs2[wave][g * 16 + col] = partial;
  }
  __syncthreads();
  const size_t pbase = ((size_t)bh * 16 + qc) * 1024;
  for (int i = tid; i < 1024; i += 256)
    part[pbase + i] = cs2[0][i] + cs2[1][i] + cs2[2][i] + cs2[3][i];
}

// ---------------------------------------------------------------------------
// Kernel C1: per-(bh, quarter) aw-reduce + partial O[d]. 256 blocks.
// ---------------------------------------------------------------------------
__global__ __launch_bounds__(256) void finalize_a(
    const float* __restrict__ part, const unsigned short* __restrict__ Vb,
    float* __restrict__ part2) {
  const int bh = blockIdx.x >> 2, g = blockIdx.x & 3;
  const int tid = threadIdx.x;
  __shared__ float aw[256];
  __shared__ float red[4][64];
  {
    const int m = g * 256 + tid;
    float a = 0.f;
#pragma unroll
    for (int qc = 0; qc < 16; ++qc)
      a += part[((size_t)bh * 16 + qc) * 1024 + m];
    aw[tid] = a;
  }
  __syncthreads();
  const int d = tid & 63, sub = tid >> 6;
  float acc = 0.f;
#pragma unroll 8
  for (int mm = 0; mm < 64; ++mm) {
    const int m = g * 256 + sub * 64 + mm;
    __hip_bfloat16 v;
    *(unsigned short*)&v = Vb[((size_t)bh * L_SEQ + m) * DQ + d];
    acc = fmaf(aw[sub * 64 + mm], __bfloat162float(v), acc);
  }
  red[sub][d] = acc;
  __syncthreads();
  if (tid < 64)
    part2[((size_t)bh * 4 + g) * 64 + tid] =
        red[0][tid] + red[1][tid] + red[2][tid] + red[3][tid];
}

// ---------------------------------------------------------------------------
// Kernel C2: reduce 4 partials + GroupNorm(d=64). One wave per bh.
// ---------------------------------------------------------------------------
__global__ __launch_bounds__(64) void finalize_b(
    const float* __restrict__ part2, const float* __restrict__ gnw,
    const float* __restrict__ gnb, float* __restrict__ out) {
  const int bh = blockIdx.x;
  const int d = threadIdx.x;
  float v = 0.f;
#pragma unroll
  for (int g = 0; g < 4; ++g) v += part2[((size_t)bh * 4 + g) * 64 + d];
  float s = v;
#pragma unroll
  for (int off = 32; off >= 1; off >>= 1) s += __shfl_xor(s, off, 64);
  float mean = s * (1.f / 64.f);
  float diff = v - mean;
  float sq = diff * diff;
#pragma unroll
  for (int off = 32; off >= 1; off >>= 1) sq += __shfl_xor(sq, off, 64);
  float var = sq * (1.f / 64.f);
  float o = diff * rsqrtf(var + 1e-5f);
  const int b = bh >> 3, h = bh & 7;
  out[(size_t)b * 512 + h * 64 + d] = o * gnw[h] + gnb[h];
}

extern "C" void kernel_launch(void* const* d_in, const int* in_sizes, int n_in,
                              void* d_out, int out_size, void* d_ws,
                              size_t ws_size, hipStream_t stream) {
  (void)in_sizes; (void)n_in; (void)out_size; (void)ws_size;
  const float* emb  = (const float*)d_in[0];
  const float* W    = (const float*)d_in[1];
  const float* bias = (const float*)d_in[2];
  const float* gnw  = (const float*)d_in[3];
  const float* gnb  = (const float*)d_in[4];
  float* out = (float*)d_out;

  char* ws = (char*)d_ws;
  const size_t perQ = (size_t)BH * L_SEQ * DQ;        // 4,194,304 elems
  unsigned short* embB = (unsigned short*)ws;                      // 8 MB
  unsigned short* WB   = (unsigned short*)(ws + 8u * 1024 * 1024); // 1.5 MB
  unsigned short* Qb   = (unsigned short*)(ws + 10u * 1024 * 1024);
  unsigned short* Kb   = Qb + perQ;
  unsigned short* Vb   = Kb + perQ;
  float* part  = (float*)(ws + 34u * 1024 * 1024);    // 4 MB
  float* part2 = (float*)(ws + 38u * 1024 * 1024);    // 64 KB

  to_bf16<<<dim3(2432), 256, 0, stream>>>(emb, W, embB, WB);
  qkv_mfma<<<dim3(NQKV / 128, 8192 / 128), 256, 0, stream>>>(
      embB, WB, bias, Qb, Kb, Vb);
  attn_2pass<<<dim3(16, BH), 256, 0, stream>>>(Qb, Kb, part);
  finalize_a<<<dim3(BH * 4), 256, 0, stream>>>(part, Vb, part2);
  finalize_b<<<dim3(BH), 64, 0, stream>>>(part2, gnw, gnb, out);
}

// Round 7
// 145.879 us; speedup vs baseline: 1.5514x; 1.5514x over previous
//
#include <hip/hip_runtime.h>
#include <hip/hip_bf16.h>
#include <math.h>

#define L_SEQ 1024
#define BSZ 8
#define EMB 512
#define NH 8
#define DQ 64
#define BH 64          // BSZ*NH
#define NQKV 1536      // 3*NH*DQ

// Q is pre-scaled by (emb_dim/n_head)^-0.5 * log2(e) so that
// softmax numerator = exp2(mfma_score) with zero extra VALU per element.
#define SCALE_Q 0.18033688f

typedef __attribute__((ext_vector_type(8))) short short8;   // 8 bf16 = 4 VGPR
typedef __attribute__((ext_vector_type(4))) float f32x4;

#define GPTR(x) ((const __attribute__((address_space(1))) void*)(x))
#define LPTR(x) ((__attribute__((address_space(3))) void*)(x))

__device__ __forceinline__ unsigned short bf16u(float x) {
  __hip_bfloat16 h = __float2bfloat16(x);
  return *(unsigned short*)&h;
}

// ---------------------------------------------------------------------------
// Kernel 0: f32 -> bf16 convert of emb (8192x512) and W (1536x512).
// ---------------------------------------------------------------------------
__global__ __launch_bounds__(256) void to_bf16(
    const float* __restrict__ emb, const float* __restrict__ W,
    unsigned short* __restrict__ embB, unsigned short* __restrict__ WB) {
  const size_t t = (size_t)blockIdx.x * 256 + threadIdx.x;
  size_t base = t * 8;
  const float* src;
  unsigned short* dst;
  size_t off;
  if (base < (size_t)8192 * 512) { src = emb; dst = embB; off = base; }
  else { src = W; dst = WB; off = base - (size_t)8192 * 512; }
  float4 v0 = *(const float4*)&src[off];
  float4 v1 = *(const float4*)&src[off + 4];
  short8 o;
  o[0] = bf16u(v0.x); o[1] = bf16u(v0.y); o[2] = bf16u(v0.z); o[3] = bf16u(v0.w);
  o[4] = bf16u(v1.x); o[5] = bf16u(v1.y); o[6] = bf16u(v1.z); o[7] = bf16u(v1.w);
  *(short8*)&dst[off] = o;
}

// ---------------------------------------------------------------------------
// Kernel A: QKV projection, bf16 MFMA (m97 pattern). Q gets SCALE_Q folded in.
// ---------------------------------------------------------------------------
__global__ __launch_bounds__(256) void qkv_mfma(
    const unsigned short* __restrict__ A,   // embB [8192][512]
    const unsigned short* __restrict__ B,   // WB   [1536][512]
    const float* __restrict__ bias,
    unsigned short* __restrict__ Qb, unsigned short* __restrict__ Kb,
    unsigned short* __restrict__ Vb) {
  __shared__ __align__(16) unsigned short As[128][32];  // 8 KB, unpadded
  __shared__ __align__(16) unsigned short Bs[128][32];  // 8 KB
  const int tid = threadIdx.x;
  const int wave = tid >> 6, lane = tid & 63;
  const int quad = lane >> 4, col = lane & 15;
  const int wr = wave >> 1, wc = wave & 1;
  const int m0 = blockIdx.y * 128, n0 = blockIdx.x * 128;
  const int r16 = lane >> 2, q4 = lane & 3;

  f32x4 acc[4][4] = {};

  for (int kt = 0; kt < EMB; kt += 32) {
    __syncthreads();
#pragma unroll
    for (int c = 0; c < 2; ++c) {
      const int rowA = (c * 4 + wave) * 16;
      __builtin_amdgcn_global_load_lds(
          GPTR(A + (size_t)(m0 + rowA + r16) * EMB + kt + q4 * 8),
          LPTR(&As[rowA][0]), 16, 0, 0);
      __builtin_amdgcn_global_load_lds(
          GPTR(B + (size_t)(n0 + rowA + r16) * EMB + kt + q4 * 8),
          LPTR(&Bs[rowA][0]), 16, 0, 0);
    }
    __syncthreads();
    short8 af[4], bf[4];
#pragma unroll
    for (int i = 0; i < 4; ++i)
      af[i] = *(const short8*)&As[wr * 64 + i * 16 + col][quad * 8];
#pragma unroll
    for (int j = 0; j < 4; ++j)
      bf[j] = *(const short8*)&Bs[wc * 64 + j * 16 + col][quad * 8];
#pragma unroll
    for (int i = 0; i < 4; ++i)
#pragma unroll
      for (int j = 0; j < 4; ++j)
        acc[i][j] =
            __builtin_amdgcn_mfma_f32_16x16x32_bf16(af[i], bf[j], acc[i][j],
                                                    0, 0, 0);
  }

#pragma unroll
  for (int j = 0; j < 4; ++j) {
    const int o = n0 + wc * 64 + j * 16 + col;
    const float bj = bias[o];
    const int h = o / 192;
    const int c2 = o - h * 192;
    const int sel = c2 >> 6, d = c2 & 63;
    unsigned short* dst = (sel == 0) ? Qb : (sel == 1) ? Kb : Vb;
#pragma unroll
    for (int i = 0; i < 4; ++i) {
      const int mrow = m0 + wr * 64 + i * 16 + quad * 4;
#pragma unroll
      for (int r = 0; r < 4; ++r) {
        const int row = mrow + r;
        const int l = row >> 3, bb = row & 7;
        float val = acc[i][j][r] + bj;
        if (sel == 0) val *= SCALE_Q;
        dst[(((size_t)(bb * NH + h)) * L_SEQ + l) * DQ + d] = bf16u(val);
      }
    }
  }
}

// ---------------------------------------------------------------------------
// Kernel B1: invz[bh][l] = 1 / sum_m exp2(s_lm).
// 1-D grid 512: bh = blk & 63 (same-bh blocks share blk%8 -> same XCD -> K
// stream stays in that XCD's L2), qc = blk >> 6 (128 q-rows per block).
// Wave owns 32 rows (qA[2][2]); K staged per 64-key tile in padded LDS
// [64][72] (144 B rows, 2-way = free); each staged fragment read feeds both
// row-groups. No cross-wave exchange: Z completes inside the wave.
// A-layout: m=lane&15, k=quad*8+j. C/D: row=quad*4+reg, col=lane&15 (m89).
// ---------------------------------------------------------------------------
__global__ __launch_bounds__(256) void attn_z(
    const unsigned short* __restrict__ Qb, const unsigned short* __restrict__ Kb,
    float* __restrict__ invz) {
  const int bh = blockIdx.x & 63;
  const int qc = blockIdx.x >> 6;           // 0..7, 128 rows each
  const int tid = threadIdx.x;
  const int wave = tid >> 6, lane = tid & 63;
  const int quad = lane >> 4, col = lane & 15;

  __shared__ __align__(16) unsigned short Ks[64][72];  // 9 KB

  const unsigned short* kbase = &Kb[(size_t)bh * L_SEQ * DQ];
  const unsigned short* qbase = &Qb[((size_t)bh * L_SEQ + qc * 128) * DQ];

  short8 qA[2][2];
#pragma unroll
  for (int rg = 0; rg < 2; ++rg) {
    const unsigned short* qp = qbase + (size_t)(wave * 32 + rg * 16 + col) * DQ;
    qA[rg][0] = *(const short8*)&qp[quad * 8];
    qA[rg][1] = *(const short8*)&qp[32 + quad * 8];
  }

  const int sr = tid >> 2;         // staging row 0..63
  const int so = (tid & 3) * 16;   // staging col offset (shorts)

  float zacc[2][4] = {};

#pragma unroll 1
  for (int kt = 0; kt < 16; ++kt) {
    __syncthreads();
    {
      const unsigned short* s8 = kbase + ((size_t)(kt * 64 + sr)) * DQ + so;
      *(short8*)&Ks[sr][so] = *(const short8*)s8;
      *(short8*)&Ks[sr][so + 8] = *(const short8*)(s8 + 8);
    }
    __syncthreads();
#pragma unroll
    for (int sub = 0; sub < 4; ++sub) {
      const unsigned short* kp = &Ks[sub * 16 + col][0];
      short8 kb0 = *(const short8*)&kp[quad * 8];
      short8 kb1 = *(const short8*)&kp[32 + quad * 8];
#pragma unroll
      for (int rg = 0; rg < 2; ++rg) {
        f32x4 s = {0.f, 0.f, 0.f, 0.f};
        s = __builtin_amdgcn_mfma_f32_16x16x32_bf16(qA[rg][0], kb0, s, 0, 0, 0);
        s = __builtin_amdgcn_mfma_f32_16x16x32_bf16(qA[rg][1], kb1, s, 0, 0, 0);
#pragma unroll
        for (int j = 0; j < 4; ++j)
          zacc[rg][j] += __builtin_amdgcn_exp2f(s[j]);
      }
    }
  }
  // butterfly over the 16 col-lanes; lane col==j writes row quad*4+j
  float* dst = &invz[(size_t)bh * L_SEQ + qc * 128];
#pragma unroll
  for (int rg = 0; rg < 2; ++rg)
#pragma unroll
    for (int j = 0; j < 4; ++j) {
      float z = zacc[rg][j];
#pragma unroll
      for (int off = 1; off <= 8; off <<= 1) z += __shfl_xor(z, off, 64);
      if (col == j)
        dst[wave * 32 + rg * 16 + quad * 4 + j] = __builtin_amdgcn_rcpf(z);
    }
}

// ---------------------------------------------------------------------------
// Kernel B2: aw[bh][m] = sum_l exp2(s_lm) * invz[bh][l].  Transposed roles:
// K rows are the A-operand (wave owns 32 keys), Q staged per 64-query tile
// in LDS, invz staged once (4 KB). Accumulate exp2(s)*invz into 8 regs;
// butterfly over query-lanes at the end; write aw directly (no part array).
// 1-D grid 512: bh = blk & 63 (XCD-local Q stream), kc = blk >> 6.
// ---------------------------------------------------------------------------
__global__ __launch_bounds__(256) void attn_aw(
    const unsigned short* __restrict__ Qb, const unsigned short* __restrict__ Kb,
    const float* __restrict__ invz, float* __restrict__ aw) {
  const int bh = blockIdx.x & 63;
  const int kc = blockIdx.x >> 6;           // 0..7, 128 keys each
  const int tid = threadIdx.x;
  const int wave = tid >> 6, lane = tid & 63;
  const int quad = lane >> 4, col = lane & 15;

  __shared__ __align__(16) unsigned short Qs[64][72];  // 9 KB
  __shared__ float izs[1024];                          // 4 KB

  const unsigned short* qbase = &Qb[(size_t)bh * L_SEQ * DQ];
  const unsigned short* kbase2 =
      &Kb[((size_t)bh * L_SEQ + kc * 128) * DQ];

  short8 kA[2][2];
#pragma unroll
  for (int kg = 0; kg < 2; ++kg) {
    const unsigned short* kp = kbase2 + (size_t)(wave * 32 + kg * 16 + col) * DQ;
    kA[kg][0] = *(const short8*)&kp[quad * 8];
    kA[kg][1] = *(const short8*)&kp[32 + quad * 8];
  }
  {  // stage invz for this bh
    const float4 v = *(const float4*)&invz[(size_t)bh * L_SEQ + tid * 4];
    *(float4*)&izs[tid * 4] = v;
  }

  const int sr = tid >> 2;
  const int so = (tid & 3) * 16;

  float acc[2][4] = {};

#pragma unroll 1
  for (int qt = 0; qt < 16; ++qt) {
    __syncthreads();
    {
      const unsigned short* s8 = qbase + ((size_t)(qt * 64 + sr)) * DQ + so;
      *(short8*)&Qs[sr][so] = *(const short8*)s8;
      *(short8*)&Qs[sr][so + 8] = *(const short8*)(s8 + 8);
    }
    __syncthreads();
#pragma unroll
    for (int sub = 0; sub < 4; ++sub) {
      const unsigned short* qp = &Qs[sub * 16 + col][0];
      short8 qb0 = *(const short8*)&qp[quad * 8];
      short8 qb1 = *(const short8*)&qp[32 + quad * 8];
      const float ivzv = izs[qt * 64 + sub * 16 + col];
#pragma unroll
      for (int kg = 0; kg < 2; ++kg) {
        f32x4 s = {0.f, 0.f, 0.f, 0.f};
        s = __builtin_amdgcn_mfma_f32_16x16x32_bf16(kA[kg][0], qb0, s, 0, 0, 0);
        s = __builtin_amdgcn_mfma_f32_16x16x32_bf16(kA[kg][1], qb1, s, 0, 0, 0);
#pragma unroll
        for (int r = 0; r < 4; ++r)
          acc[kg][r] = fmaf(__builtin_amdgcn_exp2f(s[r]), ivzv, acc[kg][r]);
      }
    }
  }
  // butterfly over the 16 query-lanes; lane col==r writes key quad*4+r
  float* dst = &aw[(size_t)bh * L_SEQ + kc * 128];
#pragma unroll
  for (int kg = 0; kg < 2; ++kg)
#pragma unroll
    for (int r = 0; r < 4; ++r) {
      float a = acc[kg][r];
#pragma unroll
      for (int off = 1; off <= 8; off <<= 1) a += __shfl_xor(a, off, 64);
      if (col == r) dst[wave * 32 + kg * 16 + quad * 4 + r] = a;
    }
}

// ---------------------------------------------------------------------------
// Kernel C: O[d] = sum_m aw[m]*V[m][d]; GroupNorm(d=64). One block per bh.
// ---------------------------------------------------------------------------
__global__ __launch_bounds__(256) void finalize(
    const float* __restrict__ aw, const unsigned short* __restrict__ Vb,
    const float* __restrict__ gnw, const float* __restrict__ gnb,
    float* __restrict__ out) {
  const int bh = blockIdx.x;
  const int tid = threadIdx.x;
  __shared__ float aws[1024];
  __shared__ float red[4][64];
  *(float4*)&aws[tid * 4] = *(const float4*)&aw[(size_t)bh * L_SEQ + tid * 4];
  __syncthreads();
  const int d = tid & 63, sub = tid >> 6;
  float acc = 0.f;
#pragma unroll 8
  for (int mm = 0; mm < 256; ++mm) {
    const int m = sub * 256 + mm;
    __hip_bfloat16 v;
    *(unsigned short*)&v = Vb[((size_t)bh * L_SEQ + m) * DQ + d];
    acc = fmaf(aws[m], __bfloat162float(v), acc);
  }
  red[sub][d] = acc;
  __syncthreads();
  if (tid < 64) {
    float v = red[0][tid] + red[1][tid] + red[2][tid] + red[3][tid];
    float s = v;
#pragma unroll
    for (int off = 32; off >= 1; off >>= 1) s += __shfl_xor(s, off, 64);
    float mean = s * (1.f / 64.f);
    float diff = v - mean;
    float sq = diff * diff;
#pragma unroll
    for (int off = 32; off >= 1; off >>= 1) sq += __shfl_xor(sq, off, 64);
    float var = sq * (1.f / 64.f);
    float o = diff * rsqrtf(var + 1e-5f);
    const int b = bh >> 3, h = bh & 7;
    out[(size_t)b * 512 + h * 64 + tid] = o * gnw[h] + gnb[h];
  }
}

extern "C" void kernel_launch(void* const* d_in, const int* in_sizes, int n_in,
                              void* d_out, int out_size, void* d_ws,
                              size_t ws_size, hipStream_t stream) {
  (void)in_sizes; (void)n_in; (void)out_size; (void)ws_size;
  const float* emb  = (const float*)d_in[0];
  const float* W    = (const float*)d_in[1];
  const float* bias = (const float*)d_in[2];
  const float* gnw  = (const float*)d_in[3];
  const float* gnb  = (const float*)d_in[4];
  float* out = (float*)d_out;

  char* ws = (char*)d_ws;
  const size_t perQ = (size_t)BH * L_SEQ * DQ;        // 4,194,304 elems
  unsigned short* embB = (unsigned short*)ws;                      // 8 MB
  unsigned short* WB   = (unsigned short*)(ws + 8u * 1024 * 1024); // 1.5 MB
  unsigned short* Qb   = (unsigned short*)(ws + 10u * 1024 * 1024);
  unsigned short* Kb   = Qb + perQ;   // @18M
  unsigned short* Vb   = Kb + perQ;   // @26M
  float* invz = (float*)(ws + 34u * 1024 * 1024);     // 256 KB
  float* aw   = (float*)(ws + 35u * 1024 * 1024);     // 256 KB

  to_bf16<<<dim3(2432), 256, 0, stream>>>(emb, W, embB, WB);
  qkv_mfma<<<dim3(NQKV / 128, 8192 / 128), 256, 0, stream>>>(
      embB, WB, bias, Qb, Kb, Vb);
  attn_z<<<dim3(512), 256, 0, stream>>>(Qb, Kb, invz);
  attn_aw<<<dim3(512), 256, 0, stream>>>(Qb, Kb, invz, aw);
  finalize<<<dim3(BH), 256, 0, stream>>>(aw, Vb, gnw, gnb, out);
}

// Round 8
// 139.006 us; speedup vs baseline: 1.6281x; 1.0494x over previous
//
#include <hip/hip_runtime.h>
#include <hip/hip_bf16.h>
#include <math.h>

#define L_SEQ 1024
#define BSZ 8
#define EMB 512
#define NH 8
#define DQ 64
#define BH 64          // BSZ*NH
#define NQKV 1536      // 3*NH*DQ

// Q is pre-scaled by (emb_dim/n_head)^-0.5 * log2(e) so that
// softmax numerator = exp2(mfma_score) with zero extra VALU per element.
#define SCALE_Q 0.18033688f

typedef __attribute__((ext_vector_type(8))) short short8;   // 8 bf16 = 4 VGPR
typedef __attribute__((ext_vector_type(4))) float f32x4;

#define GPTR(x) ((const __attribute__((address_space(1))) void*)(x))
#define LPTR(x) ((__attribute__((address_space(3))) void*)(x))

__device__ __forceinline__ unsigned short bf16u(float x) {
  __hip_bfloat16 h = __float2bfloat16(x);
  return *(unsigned short*)&h;
}

// ---------------------------------------------------------------------------
// Kernel 0: f32 -> bf16 convert of emb (8192x512) and W (1536x512).
// ---------------------------------------------------------------------------
__global__ __launch_bounds__(256) void to_bf16(
    const float* __restrict__ emb, const float* __restrict__ W,
    unsigned short* __restrict__ embB, unsigned short* __restrict__ WB) {
  const size_t t = (size_t)blockIdx.x * 256 + threadIdx.x;
  size_t base = t * 8;
  const float* src;
  unsigned short* dst;
  size_t off;
  if (base < (size_t)8192 * 512) { src = emb; dst = embB; off = base; }
  else { src = W; dst = WB; off = base - (size_t)8192 * 512; }
  float4 v0 = *(const float4*)&src[off];
  float4 v1 = *(const float4*)&src[off + 4];
  short8 o;
  o[0] = bf16u(v0.x); o[1] = bf16u(v0.y); o[2] = bf16u(v0.z); o[3] = bf16u(v0.w);
  o[4] = bf16u(v1.x); o[5] = bf16u(v1.y); o[6] = bf16u(v1.z); o[7] = bf16u(v1.w);
  *(short8*)&dst[off] = o;
}

// ---------------------------------------------------------------------------
// Kernel A: QKV projection, bf16 MFMA (m97 pattern). Q gets SCALE_Q folded in.
// Epilogue v2: C-tile staged to LDS (Cs[128][132] bf16), then each 64-col
// half-tile is a contiguous [bh][l][0..63] run -> short8 coalesced stores
// (replaces 16 scattered 2-byte stores per thread).
// ---------------------------------------------------------------------------
__global__ __launch_bounds__(256) void qkv_mfma(
    const unsigned short* __restrict__ A,   // embB [8192][512]
    const unsigned short* __restrict__ B,   // WB   [1536][512]
    const float* __restrict__ bias,
    unsigned short* __restrict__ Qb, unsigned short* __restrict__ Kb,
    unsigned short* __restrict__ Vb) {
  __shared__ __align__(16) unsigned short As[128][32];  // 8 KB, unpadded
  __shared__ __align__(16) unsigned short Bs[128][32];  // 8 KB
  __shared__ __align__(16) unsigned short Cs[128][132]; // 33 KB, +4 pad
  const int tid = threadIdx.x;
  const int wave = tid >> 6, lane = tid & 63;
  const int quad = lane >> 4, col = lane & 15;
  const int wr = wave >> 1, wc = wave & 1;
  const int m0 = blockIdx.y * 128, n0 = blockIdx.x * 128;
  const int r16 = lane >> 2, q4 = lane & 3;

  f32x4 acc[4][4] = {};

  for (int kt = 0; kt < EMB; kt += 32) {
    __syncthreads();
#pragma unroll
    for (int c = 0; c < 2; ++c) {
      const int rowA = (c * 4 + wave) * 16;
      __builtin_amdgcn_global_load_lds(
          GPTR(A + (size_t)(m0 + rowA + r16) * EMB + kt + q4 * 8),
          LPTR(&As[rowA][0]), 16, 0, 0);
      __builtin_amdgcn_global_load_lds(
          GPTR(B + (size_t)(n0 + rowA + r16) * EMB + kt + q4 * 8),
          LPTR(&Bs[rowA][0]), 16, 0, 0);
    }
    __syncthreads();
    short8 af[4], bf[4];
#pragma unroll
    for (int i = 0; i < 4; ++i)
      af[i] = *(const short8*)&As[wr * 64 + i * 16 + col][quad * 8];
#pragma unroll
    for (int j = 0; j < 4; ++j)
      bf[j] = *(const short8*)&Bs[wc * 64 + j * 16 + col][quad * 8];
#pragma unroll
    for (int i = 0; i < 4; ++i)
#pragma unroll
      for (int j = 0; j < 4; ++j)
        acc[i][j] =
            __builtin_amdgcn_mfma_f32_16x16x32_bf16(af[i], bf[j], acc[i][j],
                                                    0, 0, 0);
  }

  // ---- epilogue: acc -> Cs (bias + Q-scale, bf16). Disjoint cells, no
  // barrier needed before (Cs untouched so far). C/D: row=quad*4+reg,
  // col=lane&15 (m89-verified).
#pragma unroll
  for (int j = 0; j < 4; ++j) {
    const int n = wc * 64 + j * 16 + col;     // tile col 0..127
    const float bj = bias[n0 + n];
    const bool isQ = (((n0 + n) >> 6) % 3) == 0;
#pragma unroll
    for (int i = 0; i < 4; ++i) {
      const int mrow = wr * 64 + i * 16 + quad * 4;
#pragma unroll
      for (int r = 0; r < 4; ++r) {
        float val = acc[i][j][r] + bj;
        if (isQ) val *= SCALE_Q;
        Cs[mrow + r][n] = bf16u(val);
      }
    }
  }
  __syncthreads();
  // ---- read out. 2048 short8-chunks: (half, l, bb, oct).
  // wave handles idx=wave*8+e -> half=idx>>4, l=idx&15; lane: bb=lane>>3,
  // oct=lane&7. 8 lanes of same bb store 128 contiguous bytes.
  const int bb = lane >> 3, oct = lane & 7;
#pragma unroll
  for (int e = 0; e < 8; ++e) {
    const int idx = wave * 8 + e;
    const int half = idx >> 4, l = idx & 15;
    const int G = (n0 >> 6) + half;       // 64-col block id, 0..23
    const int h = G / 3, sel = G % 3;
    unsigned short* dst = (sel == 0) ? Qb : (sel == 1) ? Kb : Vb;
    short8 v = *(const short8*)&Cs[l * 8 + bb][half * 64 + oct * 8];
    const int lglob = (m0 >> 3) + l;      // row=m0+l*8+bb -> l_glob, bb_glob=bb
    *(short8*)&dst[(((size_t)(bb * NH + h)) * L_SEQ + lglob) * DQ + oct * 8] = v;
  }
}

// ---------------------------------------------------------------------------
// Kernel B1: invz[bh][l] = 1 / sum_m exp2(s_lm).
// Grid 512: bh = blk & 63 (same-bh blocks share blk%8 -> same XCD), qc =
// blk >> 6 (128 q-rows). Wave owns 32 rows (qA[2][2]); each staged fragment
// feeds both row-groups. v2: register-prefetch + double-buffered LDS ->
// ONE barrier per tile, global latency hidden behind compute.
// Safety: barrier(kt) implies compute(kt-1) done for all waves (program
// order compute(kt-1) < write(kt) < barrier(kt)), so writing buf kt&1 at
// iter kt never races readers of the same buf from iter kt-2.
// ---------------------------------------------------------------------------
__global__ __launch_bounds__(256) void attn_z(
    const unsigned short* __restrict__ Qb, const unsigned short* __restrict__ Kb,
    float* __restrict__ invz) {
  const int bh = blockIdx.x & 63;
  const int qc = blockIdx.x >> 6;           // 0..7, 128 rows each
  const int tid = threadIdx.x;
  const int wave = tid >> 6, lane = tid & 63;
  const int quad = lane >> 4, col = lane & 15;

  __shared__ __align__(16) unsigned short Ks[2][64][72];  // 18 KB

  const unsigned short* kbase = &Kb[(size_t)bh * L_SEQ * DQ];
  const unsigned short* qbase = &Qb[((size_t)bh * L_SEQ + qc * 128) * DQ];

  short8 qA[2][2];
#pragma unroll
  for (int rg = 0; rg < 2; ++rg) {
    const unsigned short* qp = qbase + (size_t)(wave * 32 + rg * 16 + col) * DQ;
    qA[rg][0] = *(const short8*)&qp[quad * 8];
    qA[rg][1] = *(const short8*)&qp[32 + quad * 8];
  }

  const int sr = tid >> 2;         // staging row 0..63
  const int so = (tid & 3) * 16;   // staging col offset (shorts)

  float zacc[2][4] = {};

  short8 st0, st1;
  {  // prefetch tile 0
    const unsigned short* s8 = kbase + (size_t)sr * DQ + so;
    st0 = *(const short8*)s8;
    st1 = *(const short8*)(s8 + 8);
  }

#pragma unroll 2
  for (int kt = 0; kt < 16; ++kt) {
    const int buf = kt & 1;
    *(short8*)&Ks[buf][sr][so] = st0;
    *(short8*)&Ks[buf][sr][so + 8] = st1;
    if (kt + 1 < 16) {  // prefetch next tile while this one computes
      const unsigned short* s8 =
          kbase + ((size_t)((kt + 1) * 64 + sr)) * DQ + so;
      st0 = *(const short8*)s8;
      st1 = *(const short8*)(s8 + 8);
    }
    __syncthreads();
#pragma unroll
    for (int sub = 0; sub < 4; ++sub) {
      const unsigned short* kp = &Ks[buf][sub * 16 + col][0];
      short8 kb0 = *(const short8*)&kp[quad * 8];
      short8 kb1 = *(const short8*)&kp[32 + quad * 8];
#pragma unroll
      for (int rg = 0; rg < 2; ++rg) {
        f32x4 s = {0.f, 0.f, 0.f, 0.f};
        s = __builtin_amdgcn_mfma_f32_16x16x32_bf16(qA[rg][0], kb0, s, 0, 0, 0);
        s = __builtin_amdgcn_mfma_f32_16x16x32_bf16(qA[rg][1], kb1, s, 0, 0, 0);
#pragma unroll
        for (int j = 0; j < 4; ++j)
          zacc[rg][j] += __builtin_amdgcn_exp2f(s[j]);
      }
    }
  }
  // butterfly over the 16 col-lanes; lane col==j writes row quad*4+j
  float* dst = &invz[(size_t)bh * L_SEQ + qc * 128];
#pragma unroll
  for (int rg = 0; rg < 2; ++rg)
#pragma unroll
    for (int j = 0; j < 4; ++j) {
      float z = zacc[rg][j];
#pragma unroll
      for (int off = 1; off <= 8; off <<= 1) z += __shfl_xor(z, off, 64);
      if (col == j)
        dst[wave * 32 + rg * 16 + quad * 4 + j] = __builtin_amdgcn_rcpf(z);
    }
}

// ---------------------------------------------------------------------------
// Kernel B2: aw[bh][m] = sum_l exp2(s_lm) * invz[bh][l]. Transposed roles:
// K rows are A-operand (wave owns 32 keys), Q tiles double-buffered in LDS
// with register prefetch (one barrier/tile), invz staged once (4 KB).
// Grid 512: bh = blk & 63, kc = blk >> 6.
// ---------------------------------------------------------------------------
__global__ __launch_bounds__(256) void attn_aw(
    const unsigned short* __restrict__ Qb, const unsigned short* __restrict__ Kb,
    const float* __restrict__ invz, float* __restrict__ aw) {
  const int bh = blockIdx.x & 63;
  const int kc = blockIdx.x >> 6;           // 0..7, 128 keys each
  const int tid = threadIdx.x;
  const int wave = tid >> 6, lane = tid & 63;
  const int quad = lane >> 4, col = lane & 15;

  __shared__ __align__(16) unsigned short Qs[2][64][72];  // 18 KB
  __shared__ float izs[1024];                             // 4 KB

  const unsigned short* qbase = &Qb[(size_t)bh * L_SEQ * DQ];
  const unsigned short* kbase2 = &Kb[((size_t)bh * L_SEQ + kc * 128) * DQ];

  short8 kA[2][2];
#pragma unroll
  for (int kg = 0; kg < 2; ++kg) {
    const unsigned short* kp = kbase2 + (size_t)(wave * 32 + kg * 16 + col) * DQ;
    kA[kg][0] = *(const short8*)&kp[quad * 8];
    kA[kg][1] = *(const short8*)&kp[32 + quad * 8];
  }
  {  // stage invz for this bh (visible after first in-loop barrier)
    const float4 v = *(const float4*)&invz[(size_t)bh * L_SEQ + tid * 4];
    *(float4*)&izs[tid * 4] = v;
  }

  const int sr = tid >> 2;
  const int so = (tid & 3) * 16;

  float acc[2][4] = {};

  short8 st0, st1;
  {  // prefetch tile 0
    const unsigned short* s8 = qbase + (size_t)sr * DQ + so;
    st0 = *(const short8*)s8;
    st1 = *(const short8*)(s8 + 8);
  }

#pragma unroll 2
  for (int qt = 0; qt < 16; ++qt) {
    const int buf = qt & 1;
    *(short8*)&Qs[buf][sr][so] = st0;
    *(short8*)&Qs[buf][sr][so + 8] = st1;
    if (qt + 1 < 16) {
      const unsigned short* s8 =
          qbase + ((size_t)((qt + 1) * 64 + sr)) * DQ + so;
      st0 = *(const short8*)s8;
      st1 = *(const short8*)(s8 + 8);
    }
    __syncthreads();
#pragma unroll
    for (int sub = 0; sub < 4; ++sub) {
      const unsigned short* qp = &Qs[buf][sub * 16 + col][0];
      short8 qb0 = *(const short8*)&qp[quad * 8];
      short8 qb1 = *(const short8*)&qp[32 + quad * 8];
      const float ivzv = izs[qt * 64 + sub * 16 + col];
#pragma unroll
      for (int kg = 0; kg < 2; ++kg) {
        f32x4 s = {0.f, 0.f, 0.f, 0.f};
        s = __builtin_amdgcn_mfma_f32_16x16x32_bf16(kA[kg][0], qb0, s, 0, 0, 0);
        s = __builtin_amdgcn_mfma_f32_16x16x32_bf16(kA[kg][1], qb1, s, 0, 0, 0);
#pragma unroll
        for (int r = 0; r < 4; ++r)
          acc[kg][r] = fmaf(__builtin_amdgcn_exp2f(s[r]), ivzv, acc[kg][r]);
      }
    }
  }
  // butterfly over the 16 query-lanes; lane col==r writes key quad*4+r
  float* dst = &aw[(size_t)bh * L_SEQ + kc * 128];
#pragma unroll
  for (int kg = 0; kg < 2; ++kg)
#pragma unroll
    for (int r = 0; r < 4; ++r) {
      float a = acc[kg][r];
#pragma unroll
      for (int off = 1; off <= 8; off <<= 1) a += __shfl_xor(a, off, 64);
      if (col == r) dst[wave * 32 + kg * 16 + quad * 4 + r] = a;
    }
}

// ---------------------------------------------------------------------------
// Kernel C: O[d] = sum_m aw[m]*V[m][d]; GroupNorm(d=64). One block per bh.
// ---------------------------------------------------------------------------
__global__ __launch_bounds__(256) void finalize(
    const float* __restrict__ aw, const unsigned short* __restrict__ Vb,
    const float* __restrict__ gnw, const float* __restrict__ gnb,
    float* __restrict__ out) {
  const int bh = blockIdx.x;
  const int tid = threadIdx.x;
  __shared__ float aws[1024];
  __shared__ float red[4][64];
  *(float4*)&aws[tid * 4] = *(const float4*)&aw[(size_t)bh * L_SEQ + tid * 4];
  __syncthreads();
  const int d = tid & 63, sub = tid >> 6;
  float acc = 0.f;
#pragma unroll 8
  for (int mm = 0; mm < 256; ++mm) {
    const int m = sub * 256 + mm;
    __hip_bfloat16 v;
    *(unsigned short*)&v = Vb[((size_t)bh * L_SEQ + m) * DQ + d];
    acc = fmaf(aws[m], __bfloat162float(v), acc);
  }
  red[sub][d] = acc;
  __syncthreads();
  if (tid < 64) {
    float v = red[0][tid] + red[1][tid] + red[2][tid] + red[3][tid];
    float s = v;
#pragma unroll
    for (int off = 32; off >= 1; off >>= 1) s += __shfl_xor(s, off, 64);
    float mean = s * (1.f / 64.f);
    float diff = v - mean;
    float sq = diff * diff;
#pragma unroll
    for (int off = 32; off >= 1; off >>= 1) sq += __shfl_xor(sq, off, 64);
    float var = sq * (1.f / 64.f);
    float o = diff * rsqrtf(var + 1e-5f);
    const int b = bh >> 3, h = bh & 7;
    out[(size_t)b * 512 + h * 64 + tid] = o * gnw[h] + gnb[h];
  }
}

extern "C" void kernel_launch(void* const* d_in, const int* in_sizes, int n_in,
                              void* d_out, int out_size, void* d_ws,
                              size_t ws_size, hipStream_t stream) {
  (void)in_sizes; (void)n_in; (void)out_size; (void)ws_size;
  const float* emb  = (const float*)d_in[0];
  const float* W    = (const float*)d_in[1];
  const float* bias = (const float*)d_in[2];
  const float* gnw  = (const float*)d_in[3];
  const float* gnb  = (const float*)d_in[4];
  float* out = (float*)d_out;

  char* ws = (char*)d_ws;
  const size_t perQ = (size_t)BH * L_SEQ * DQ;        // 4,194,304 elems
  unsigned short* embB = (unsigned short*)ws;                      // 8 MB
  unsigned short* WB   = (unsigned short*)(ws + 8u * 1024 * 1024); // 1.5 MB
  unsigned short* Qb   = (unsigned short*)(ws + 10u * 1024 * 1024);
  unsigned short* Kb   = Qb + perQ;   // @18M
  unsigned short* Vb   = Kb + perQ;   // @26M
  float* invz = (float*)(ws + 34u * 1024 * 1024);     // 256 KB
  float* aw   = (float*)(ws + 35u * 1024 * 1024);     // 256 KB

  to_bf16<<<dim3(2432), 256, 0, stream>>>(emb, W, embB, WB);
  qkv_mfma<<<dim3(NQKV / 128, 8192 / 128), 256, 0, stream>>>(
      embB, WB, bias, Qb, Kb, Vb);
  attn_z<<<dim3(512), 256, 0, stream>>>(Qb, Kb, invz);
  attn_aw<<<dim3(512), 256, 0, stream>>>(Qb, Kb, invz, aw);
  finalize<<<dim3(BH), 256, 0, stream>>>(aw, Vb, gnw, gnb, out);
}

// Round 9
// 136.398 us; speedup vs baseline: 1.6592x; 1.0191x over previous
//
#include <hip/hip_runtime.h>
#include <hip/hip_bf16.h>
#include <math.h>

#define L_SEQ 1024
#define BSZ 8
#define EMB 512
#define NH 8
#define DQ 64
#define BH 64          // BSZ*NH
#define NQKV 1536      // 3*NH*DQ

// Q is pre-scaled by (emb_dim/n_head)^-0.5 * log2(e) so that
// softmax numerator = exp2(mfma_score) with zero extra VALU per element.
#define SCALE_Q 0.18033688f

typedef __attribute__((ext_vector_type(8))) short short8;   // 8 bf16 = 4 VGPR
typedef __attribute__((ext_vector_type(4))) float f32x4;

#define GPTR(x) ((const __attribute__((address_space(1))) void*)(x))
#define LPTR(x) ((__attribute__((address_space(3))) void*)(x))

__device__ __forceinline__ unsigned short bf16u(float x) {
  __hip_bfloat16 h = __float2bfloat16(x);
  return *(unsigned short*)&h;
}

// ---------------------------------------------------------------------------
// Kernel 0: f32 -> bf16 convert of emb (8192x512) and W (1536x512).
// ---------------------------------------------------------------------------
__global__ __launch_bounds__(256) void to_bf16(
    const float* __restrict__ emb, const float* __restrict__ W,
    unsigned short* __restrict__ embB, unsigned short* __restrict__ WB) {
  const size_t t = (size_t)blockIdx.x * 256 + threadIdx.x;
  size_t base = t * 8;
  const float* src;
  unsigned short* dst;
  size_t off;
  if (base < (size_t)8192 * 512) { src = emb; dst = embB; off = base; }
  else { src = W; dst = WB; off = base - (size_t)8192 * 512; }
  float4 v0 = *(const float4*)&src[off];
  float4 v1 = *(const float4*)&src[off + 4];
  short8 o;
  o[0] = bf16u(v0.x); o[1] = bf16u(v0.y); o[2] = bf16u(v0.z); o[3] = bf16u(v0.w);
  o[4] = bf16u(v1.x); o[5] = bf16u(v1.y); o[6] = bf16u(v1.z); o[7] = bf16u(v1.w);
  *(short8*)&dst[off] = o;
}

// ---------------------------------------------------------------------------
// Kernel A: QKV projection, bf16 MFMA (m97 pattern). Q gets SCALE_Q folded in.
// Epilogue: C-tile staged to LDS (Cs[128][132] bf16), then each 64-col
// half-tile is a contiguous [bh][l][0..63] run -> short8 coalesced stores.
// ---------------------------------------------------------------------------
__global__ __launch_bounds__(256) void qkv_mfma(
    const unsigned short* __restrict__ A,   // embB [8192][512]
    const unsigned short* __restrict__ B,   // WB   [1536][512]
    const float* __restrict__ bias,
    unsigned short* __restrict__ Qb, unsigned short* __restrict__ Kb,
    unsigned short* __restrict__ Vb) {
  __shared__ __align__(16) unsigned short As[128][32];  // 8 KB, unpadded
  __shared__ __align__(16) unsigned short Bs[128][32];  // 8 KB
  __shared__ __align__(16) unsigned short Cs[128][132]; // 33 KB, +4 pad
  const int tid = threadIdx.x;
  const int wave = tid >> 6, lane = tid & 63;
  const int quad = lane >> 4, col = lane & 15;
  const int wr = wave >> 1, wc = wave & 1;
  const int m0 = blockIdx.y * 128, n0 = blockIdx.x * 128;
  const int r16 = lane >> 2, q4 = lane & 3;

  f32x4 acc[4][4] = {};

  for (int kt = 0; kt < EMB; kt += 32) {
    __syncthreads();
#pragma unroll
    for (int c = 0; c < 2; ++c) {
      const int rowA = (c * 4 + wave) * 16;
      __builtin_amdgcn_global_load_lds(
          GPTR(A + (size_t)(m0 + rowA + r16) * EMB + kt + q4 * 8),
          LPTR(&As[rowA][0]), 16, 0, 0);
      __builtin_amdgcn_global_load_lds(
          GPTR(B + (size_t)(n0 + rowA + r16) * EMB + kt + q4 * 8),
          LPTR(&Bs[rowA][0]), 16, 0, 0);
    }
    __syncthreads();
    short8 af[4], bf[4];
#pragma unroll
    for (int i = 0; i < 4; ++i)
      af[i] = *(const short8*)&As[wr * 64 + i * 16 + col][quad * 8];
#pragma unroll
    for (int j = 0; j < 4; ++j)
      bf[j] = *(const short8*)&Bs[wc * 64 + j * 16 + col][quad * 8];
#pragma unroll
    for (int i = 0; i < 4; ++i)
#pragma unroll
      for (int j = 0; j < 4; ++j)
        acc[i][j] =
            __builtin_amdgcn_mfma_f32_16x16x32_bf16(af[i], bf[j], acc[i][j],
                                                    0, 0, 0);
  }

#pragma unroll
  for (int j = 0; j < 4; ++j) {
    const int n = wc * 64 + j * 16 + col;     // tile col 0..127
    const float bj = bias[n0 + n];
    const bool isQ = (((n0 + n) >> 6) % 3) == 0;
#pragma unroll
    for (int i = 0; i < 4; ++i) {
      const int mrow = wr * 64 + i * 16 + quad * 4;
#pragma unroll
      for (int r = 0; r < 4; ++r) {
        float val = acc[i][j][r] + bj;
        if (isQ) val *= SCALE_Q;
        Cs[mrow + r][n] = bf16u(val);
      }
    }
  }
  __syncthreads();
  const int bb = lane >> 3, oct = lane & 7;
#pragma unroll
  for (int e = 0; e < 8; ++e) {
    const int idx = wave * 8 + e;
    const int half = idx >> 4, l = idx & 15;
    const int G = (n0 >> 6) + half;       // 64-col block id, 0..23
    const int h = G / 3, sel = G % 3;
    unsigned short* dst = (sel == 0) ? Qb : (sel == 1) ? Kb : Vb;
    short8 v = *(const short8*)&Cs[l * 8 + bb][half * 64 + oct * 8];
    const int lglob = (m0 >> 3) + l;
    *(short8*)&dst[(((size_t)(bb * NH + h)) * L_SEQ + lglob) * DQ + oct * 8] = v;
  }
}

// ---------------------------------------------------------------------------
// Kernel B1: invz[bh][l] = 1 / sum_m exp2(s_lm). Also zero-inits the O
// accumulator and per-bh block counter (visible to attn_aw via the implicit
// kernel-boundary cache flush). Double-buffered LDS, register prefetch,
// one barrier/tile. Grid 512: bh = blk & 63 (XCD-local K stream).
// ---------------------------------------------------------------------------
__global__ __launch_bounds__(256) void attn_z(
    const unsigned short* __restrict__ Qb, const unsigned short* __restrict__ Kb,
    float* __restrict__ invz, float* __restrict__ Oacc, int* __restrict__ cnt) {
  const int bh = blockIdx.x & 63;
  const int qc = blockIdx.x >> 6;           // 0..7, 128 rows each
  const int tid = threadIdx.x;
  const int wave = tid >> 6, lane = tid & 63;
  const int quad = lane >> 4, col = lane & 15;

  __shared__ __align__(16) unsigned short Ks[2][64][72];  // 18 KB

  if (qc == 0) {  // one block per bh zero-inits O and cnt
    if (tid < 64) Oacc[(size_t)bh * 64 + tid] = 0.f;
    if (tid == 0) cnt[bh] = 0;
  }

  const unsigned short* kbase = &Kb[(size_t)bh * L_SEQ * DQ];
  const unsigned short* qbase = &Qb[((size_t)bh * L_SEQ + qc * 128) * DQ];

  short8 qA[2][2];
#pragma unroll
  for (int rg = 0; rg < 2; ++rg) {
    const unsigned short* qp = qbase + (size_t)(wave * 32 + rg * 16 + col) * DQ;
    qA[rg][0] = *(const short8*)&qp[quad * 8];
    qA[rg][1] = *(const short8*)&qp[32 + quad * 8];
  }

  const int sr = tid >> 2;         // staging row 0..63
  const int so = (tid & 3) * 16;   // staging col offset (shorts)

  float zacc[2][4] = {};

  short8 st0, st1;
  {  // prefetch tile 0
    const unsigned short* s8 = kbase + (size_t)sr * DQ + so;
    st0 = *(const short8*)s8;
    st1 = *(const short8*)(s8 + 8);
  }

#pragma unroll 2
  for (int kt = 0; kt < 16; ++kt) {
    const int buf = kt & 1;
    *(short8*)&Ks[buf][sr][so] = st0;
    *(short8*)&Ks[buf][sr][so + 8] = st1;
    if (kt + 1 < 16) {
      const unsigned short* s8 =
          kbase + ((size_t)((kt + 1) * 64 + sr)) * DQ + so;
      st0 = *(const short8*)s8;
      st1 = *(const short8*)(s8 + 8);
    }
    __syncthreads();
#pragma unroll
    for (int sub = 0; sub < 4; ++sub) {
      const unsigned short* kp = &Ks[buf][sub * 16 + col][0];
      short8 kb0 = *(const short8*)&kp[quad * 8];
      short8 kb1 = *(const short8*)&kp[32 + quad * 8];
#pragma unroll
      for (int rg = 0; rg < 2; ++rg) {
        f32x4 s = {0.f, 0.f, 0.f, 0.f};
        s = __builtin_amdgcn_mfma_f32_16x16x32_bf16(qA[rg][0], kb0, s, 0, 0, 0);
        s = __builtin_amdgcn_mfma_f32_16x16x32_bf16(qA[rg][1], kb1, s, 0, 0, 0);
#pragma unroll
        for (int j = 0; j < 4; ++j)
          zacc[rg][j] += __builtin_amdgcn_exp2f(s[j]);
      }
    }
  }
  float* dst = &invz[(size_t)bh * L_SEQ + qc * 128];
#pragma unroll
  for (int rg = 0; rg < 2; ++rg)
#pragma unroll
    for (int j = 0; j < 4; ++j) {
      float z = zacc[rg][j];
#pragma unroll
      for (int off = 1; off <= 8; off <<= 1) z += __shfl_xor(z, off, 64);
      if (col == j)
        dst[wave * 32 + rg * 16 + quad * 4 + j] = __builtin_amdgcn_rcpf(z);
    }
}

// ---------------------------------------------------------------------------
// Kernel B2 (fused): aw chunk -> local V-combine -> atomic O accumulate ->
// last block per bh does GroupNorm + output write.
// Block (bh,kc) owns keys kc*128..+127: aw values go to LDS, then
// O_part[d] = sum_m aws[m]*V[m][d] over exactly those keys (16 KB of V,
// disjoint across blocks), atomicAdd'ed into Oacc[bh][d] (device-scope,
// G16-safe). cnt[bh] release/acquire via __threadfence + atomicAdd; the
// 8th block reads Oacc coherently with atomicAdd(&x, 0.f) and normalizes.
// ---------------------------------------------------------------------------
__global__ __launch_bounds__(256) void attn_aw(
    const unsigned short* __restrict__ Qb, const unsigned short* __restrict__ Kb,
    const unsigned short* __restrict__ Vb, const float* __restrict__ invz,
    const float* __restrict__ gnw, const float* __restrict__ gnb,
    float* __restrict__ Oacc, int* __restrict__ cnt, float* __restrict__ out) {
  const int bh = blockIdx.x & 63;
  const int kc = blockIdx.x >> 6;           // 0..7, 128 keys each
  const int tid = threadIdx.x;
  const int wave = tid >> 6, lane = tid & 63;
  const int quad = lane >> 4, col = lane & 15;

  __shared__ __align__(16) unsigned short Qs[2][64][72];  // 18 KB
  __shared__ float izs[1024];                             // 4 KB
  __shared__ float aws[128];
  __shared__ float red[4][64];
  __shared__ int lastFlag;

  const unsigned short* qbase = &Qb[(size_t)bh * L_SEQ * DQ];
  const unsigned short* kbase2 = &Kb[((size_t)bh * L_SEQ + kc * 128) * DQ];

  short8 kA[2][2];
#pragma unroll
  for (int kg = 0; kg < 2; ++kg) {
    const unsigned short* kp = kbase2 + (size_t)(wave * 32 + kg * 16 + col) * DQ;
    kA[kg][0] = *(const short8*)&kp[quad * 8];
    kA[kg][1] = *(const short8*)&kp[32 + quad * 8];
  }
  {  // stage invz for this bh (visible after first in-loop barrier)
    const float4 v = *(const float4*)&invz[(size_t)bh * L_SEQ + tid * 4];
    *(float4*)&izs[tid * 4] = v;
  }

  const int sr = tid >> 2;
  const int so = (tid & 3) * 16;

  float acc[2][4] = {};

  short8 st0, st1;
  {  // prefetch tile 0
    const unsigned short* s8 = qbase + (size_t)sr * DQ + so;
    st0 = *(const short8*)s8;
    st1 = *(const short8*)(s8 + 8);
  }

#pragma unroll 2
  for (int qt = 0; qt < 16; ++qt) {
    const int buf = qt & 1;
    *(short8*)&Qs[buf][sr][so] = st0;
    *(short8*)&Qs[buf][sr][so + 8] = st1;
    if (qt + 1 < 16) {
      const unsigned short* s8 =
          qbase + ((size_t)((qt + 1) * 64 + sr)) * DQ + so;
      st0 = *(const short8*)s8;
      st1 = *(const short8*)(s8 + 8);
    }
    __syncthreads();
#pragma unroll
    for (int sub = 0; sub < 4; ++sub) {
      const unsigned short* qp = &Qs[buf][sub * 16 + col][0];
      short8 qb0 = *(const short8*)&qp[quad * 8];
      short8 qb1 = *(const short8*)&qp[32 + quad * 8];
      const float ivzv = izs[qt * 64 + sub * 16 + col];
#pragma unroll
      for (int kg = 0; kg < 2; ++kg) {
        f32x4 s = {0.f, 0.f, 0.f, 0.f};
        s = __builtin_amdgcn_mfma_f32_16x16x32_bf16(kA[kg][0], qb0, s, 0, 0, 0);
        s = __builtin_amdgcn_mfma_f32_16x16x32_bf16(kA[kg][1], qb1, s, 0, 0, 0);
#pragma unroll
        for (int r = 0; r < 4; ++r)
          acc[kg][r] = fmaf(__builtin_amdgcn_exp2f(s[r]), ivzv, acc[kg][r]);
      }
    }
  }
  // butterfly over the 16 query-lanes; lane col==r holds key quad*4+r
#pragma unroll
  for (int kg = 0; kg < 2; ++kg)
#pragma unroll
    for (int r = 0; r < 4; ++r) {
      float a = acc[kg][r];
#pragma unroll
      for (int off = 1; off <= 8; off <<= 1) a += __shfl_xor(a, off, 64);
      if (col == r) aws[wave * 32 + kg * 16 + quad * 4 + r] = a;
    }
  __syncthreads();

  // local V-combine over this block's 128 keys
  const int d = tid & 63, sub4 = tid >> 6;  // 4 subs x 32 keys
  float oacc = 0.f;
#pragma unroll 8
  for (int mm = 0; mm < 32; ++mm) {
    const int m = sub4 * 32 + mm;
    __hip_bfloat16 v;
    *(unsigned short*)&v =
        Vb[((size_t)bh * L_SEQ + kc * 128 + m) * DQ + d];
    oacc = fmaf(aws[m], __bfloat162float(v), oacc);
  }
  red[sub4][d] = oacc;
  __syncthreads();
  if (tid < 64) {
    float p = red[0][tid] + red[1][tid] + red[2][tid] + red[3][tid];
    atomicAdd(&Oacc[(size_t)bh * 64 + tid], p);
  }
  if (tid == 0) {
    __threadfence();                      // release: O adds visible first
    lastFlag = (atomicAdd(&cnt[bh], 1) == 7);
  }
  __syncthreads();
  if (lastFlag && tid < 64) {
    __threadfence();                      // acquire
    // coherent read of the fully-accumulated O
    float v = atomicAdd(&Oacc[(size_t)bh * 64 + tid], 0.f);
    float s = v;
#pragma unroll
    for (int off = 32; off >= 1; off >>= 1) s += __shfl_xor(s, off, 64);
    float mean = s * (1.f / 64.f);
    float diff = v - mean;
    float sq = diff * diff;
#pragma unroll
    for (int off = 32; off >= 1; off >>= 1) sq += __shfl_xor(sq, off, 64);
    float var = sq * (1.f / 64.f);
    float o = diff * rsqrtf(var + 1e-5f);
    const int b = bh >> 3, h = bh & 7;
    out[(size_t)b * 512 + h * 64 + tid] = o * gnw[h] + gnb[h];
  }
}

extern "C" void kernel_launch(void* const* d_in, const int* in_sizes, int n_in,
                              void* d_out, int out_size, void* d_ws,
                              size_t ws_size, hipStream_t stream) {
  (void)in_sizes; (void)n_in; (void)out_size; (void)ws_size;
  const float* emb  = (const float*)d_in[0];
  const float* W    = (const float*)d_in[1];
  const float* bias = (const float*)d_in[2];
  const float* gnw  = (const float*)d_in[3];
  const float* gnb  = (const float*)d_in[4];
  float* out = (float*)d_out;

  char* ws = (char*)d_ws;
  const size_t perQ = (size_t)BH * L_SEQ * DQ;        // 4,194,304 elems
  unsigned short* embB = (unsigned short*)ws;                      // 8 MB
  unsigned short* WB   = (unsigned short*)(ws + 8u * 1024 * 1024); // 1.5 MB
  unsigned short* Qb   = (unsigned short*)(ws + 10u * 1024 * 1024);
  unsigned short* Kb   = Qb + perQ;   // @18M
  unsigned short* Vb   = Kb + perQ;   // @26M
  float* invz = (float*)(ws + 34u * 1024 * 1024);     // 256 KB
  float* Oacc = (float*)(ws + 35u * 1024 * 1024);     // 16 KB
  int*   cnt  = (int*)(ws + 35u * 1024 * 1024 + 64u * 1024);

  to_bf16<<<dim3(2432), 256, 0, stream>>>(emb, W, embB, WB);
  qkv_mfma<<<dim3(NQKV / 128, 8192 / 128), 256, 0, stream>>>(
      embB, WB, bias, Qb, Kb, Vb);
  attn_z<<<dim3(512), 256, 0, stream>>>(Qb, Kb, invz, Oacc, cnt);
  attn_aw<<<dim3(512), 256, 0, stream>>>(Qb, Kb, Vb, invz, gnw, gnb,
                                         Oacc, cnt, out);
}